// Round 5
// baseline (671.764 us; speedup 1.0000x reference)
//
#include <hip/hip_runtime.h>
#include <stdint.h>

// Problem constants
#define BATCH 512
#define HWIMG 78400      // 280*280
#define WROW  280
#define PNUM  100        // 10x10 patches
#define FNUM  16
#define ONUM  10

typedef __attribute__((address_space(1))) const void cg_void;
typedef __attribute__((address_space(3))) void lds_void;

__global__ __launch_bounds__(256) void init_out(const float* __restrict__ dec_b,
                                                float* __restrict__ out) {
    int i = blockIdx.x * 256 + threadIdx.x;
    if (i < BATCH * ONUM) out[i] = dec_b[i % ONUM];
}

// Block = (pr, pent, 16 batches): pr = patch-row band (28 contiguous image rows),
// pent = which 5 of the 10 patch-columns. Chunk = ONE image row: x staged as
// 16 x 560-B CONTIGUOUS runs (dense DRAM streams), w staged as 80 x 112-B segs.
// 256 threads = kg8 x fg4 x bg8; per lane: i=2 batches, j=4 filters, 5 pc.
//
// DMA discipline (round-3 failure fix): ALL global_load_lds ops are FULL-EXEC
// 64-lane — the LDS-write side is wave-uniform base + lane*16 and is NOT safely
// exec-maskable. The 140-f4 per-wave range is covered by 3 ops of 64; op k=2's
// lanes 12..63 spill into wave w+1's leading slots WITH IDENTICAL SOURCE DATA
// (benign duplicate write), and wave 3's tail (gi 560..611) lands in a 56-f4 PAD
// (buffers are [616] not [560]) so it can never corrupt the other dbuf half.
// 6 uniform DMA ops/wave/chunk -> vmcnt(6) keeps next chunk's 6 in flight.
// LDS 39.4KB -> 4 blocks/CU (16 waves).
__global__ __launch_bounds__(256, 4) void lcn_rows(
    const float* __restrict__ x,      // (512,1,280,280)
    const float* __restrict__ weight, // (1600,1,28,28)  index (f*100+p)*784
    const float* __restrict__ bias,   // (1600,1)        index  f*100+p
    const float* __restrict__ dec_w,  // (10,1600)       index  o*1600+f*100+p
    float* __restrict__ out)          // (512,10) pre-initialized with dec_b
{
    __shared__ float4 lx[2][616];   // [buf][b*35 + off] b=0..15, off=0..34; 560..615 pad
    __shared__ float4 lw[2][616];   // [buf][(f*5+pc)*7 + k] f=0..15, pc=0..4; pad

    const int t  = threadIdx.x;
    const int kg = t & 7;             // k-column (f4) within the 5-pc window
    const int fg = (t >> 3) & 3;      // filter quad
    const int bg = t >> 5;            // batch pair 0..7
    const int wid = t >> 6;           // wave 0..3
    const int ln  = t & 63;

    const int bx   = blockIdx.x;      // 0..639
    const int pent = bx & 1;          // pent pairs adjacent -> combined full-row streams
    const int bgrp = (bx >> 1) & 31;
    const int pr   = bx >> 6;         // 0..9 (64 consecutive blocks share pr's weights)
    const int b0   = bgrp * 16;
    const int kge  = (kg < 7) ? kg : 0;   // kg==7 duplicates kg==0, masked later

    // ---- DMA sources: wave w stages f4-range [w*140, w*140+140) of lx and lw,
    // as 3 full-exec ops (64+64+64 lanes; op 2's lanes 12..63 duplicate wave w+1's
    // data / write pad — see header comment). Per-lane divs done ONCE here;
    // per-chunk advance is uniform (+1120B x, +112B w).
    const float* xsrc[3];
    const float* wsrc[3];
#pragma unroll
    for (int k = 0; k < 3; ++k) {
        int gi = wid * 140 + k * 64 + ln;
        if (gi > 559) gi = 559;                    // wave-3 tail -> pad slots, clamped src
        const int b   = gi / 35;                   // local batch 0..15
        const int off = gi % 35;                   // f4 within 560-B run
        xsrc[k] = x + (size_t)(b0 + b) * HWIMG + (size_t)(pr * 28) * WROW
                    + pent * 140 + off * 4;
        const int seg = gi / 7;                    // (f*5+pc) 0..79
        const int o7  = gi % 7;
        const int f   = seg / 5;
        const int pcl = seg % 5;
        const int p   = pr * 10 + pent * 5 + pcl;
        wsrc[k] = weight + (size_t)(f * PNUM + p) * 784 + o7 * 4;
    }

    auto issue = [&](int bb) {
#pragma unroll
        for (int k = 0; k < 3; ++k)
            __builtin_amdgcn_global_load_lds((cg_void*)xsrc[k],
                (lds_void*)&lx[bb][wid * 140 + k * 64 + ln], 16, 0, 0);
#pragma unroll
        for (int k = 0; k < 3; ++k)
            __builtin_amdgcn_global_load_lds((cg_void*)wsrc[k],
                (lds_void*)&lw[bb][wid * 140 + k * 64 + ln], 16, 0, 0);
        // advance to next image row
#pragma unroll
        for (int k = 0; k < 3; ++k) { xsrc[k] += WROW; wsrc[k] += 28; }
    };

    float acc[5][2][4];
#pragma unroll
    for (int pc = 0; pc < 5; ++pc)
#pragma unroll
        for (int i = 0; i < 2; ++i)
#pragma unroll
            for (int j = 0; j < 4; ++j) acc[pc][i][j] = 0.f;

    issue(0);
    issue(1);

#pragma unroll 1
    for (int c = 0; c < 28; ++c) {
        const int buf = c & 1;
        // chunk c's 6 DMA done; chunk c+1's 6 stay in flight
        if (c < 27) asm volatile("s_waitcnt vmcnt(6)" ::: "memory");
        else        asm volatile("s_waitcnt vmcnt(0)" ::: "memory");
        __builtin_amdgcn_s_barrier();
        asm volatile("" ::: "memory");

#pragma unroll
        for (int pc = 0; pc < 5; ++pc) {
            float4 wvv[4];
#pragma unroll
            for (int j = 0; j < 4; ++j)
                wvv[j] = lw[buf][((fg * 4 + j) * 5 + pc) * 7 + kge];
#pragma unroll
            for (int i = 0; i < 2; ++i) {
                const float4 av = lx[buf][(bg * 2 + i) * 35 + pc * 7 + kge];
#pragma unroll
                for (int j = 0; j < 4; ++j) {
                    acc[pc][i][j] = fmaf(av.x, wvv[j].x, acc[pc][i][j]);
                    acc[pc][i][j] = fmaf(av.y, wvv[j].y, acc[pc][i][j]);
                    acc[pc][i][j] = fmaf(av.z, wvv[j].z, acc[pc][i][j]);
                    acc[pc][i][j] = fmaf(av.w, wvv[j].w, acc[pc][i][j]);
                }
            }
        }

        asm volatile("" ::: "memory");
        __builtin_amdgcn_s_barrier();        // all waves done reading buf
        if (c + 2 < 28) issue(buf);
    }

    // kg==7 computed duplicated (kg==0) data: zero it.
    const float km = (kg < 7) ? 1.f : 0.f;
#pragma unroll
    for (int pc = 0; pc < 5; ++pc)
#pragma unroll
        for (int i = 0; i < 2; ++i)
#pragma unroll
            for (int j = 0; j < 4; ++j) acc[pc][i][j] *= km;

    // Reduce over kg (lane bits 0..2) — butterfly; all lanes end with full sums.
#pragma unroll
    for (int d = 1; d < 8; d <<= 1)
#pragma unroll
        for (int pc = 0; pc < 5; ++pc)
#pragma unroll
            for (int i = 0; i < 2; ++i)
#pragma unroll
                for (int j = 0; j < 4; ++j)
                    acc[pc][i][j] += __shfl_xor(acc[pc][i][j], d, 64);

    // bias + relu (in place)
#pragma unroll
    for (int pc = 0; pc < 5; ++pc) {
        const int p = pr * 10 + pent * 5 + pc;
#pragma unroll
        for (int j = 0; j < 4; ++j) {
            const float bs = bias[(fg * 4 + j) * PNUM + p];
#pragma unroll
            for (int i = 0; i < 2; ++i) {
                float v = acc[pc][i][j] + bs;
                acc[pc][i][j] = v > 0.f ? v : 0.f;
            }
        }
    }

    // Decoder: 10 outputs split across kg lanes 0..4 (2 each).
    float po[2][2];
    const int  o0  = kg * 2;
    const bool act = (kg < 5);
    if (act) {
#pragma unroll
        for (int i = 0; i < 2; ++i) { po[i][0] = 0.f; po[i][1] = 0.f; }
#pragma unroll
        for (int pc = 0; pc < 5; ++pc) {
            const int p = pr * 10 + pent * 5 + pc;
#pragma unroll
            for (int j = 0; j < 4; ++j) {
                const int fidx = (fg * 4 + j) * PNUM + p;
#pragma unroll
                for (int oo = 0; oo < 2; ++oo) {
                    const float dw = dec_w[(size_t)(o0 + oo) * (PNUM * FNUM) + fidx];
#pragma unroll
                    for (int i = 0; i < 2; ++i)
                        po[i][oo] = fmaf(acc[pc][i][j], dw, po[i][oo]);
                }
            }
        }
    } else {
#pragma unroll
        for (int i = 0; i < 2; ++i) { po[i][0] = 0.f; po[i][1] = 0.f; }
    }

    // Reduce over fg (lane bits 3..4); kg/bg bits preserved.
#pragma unroll
    for (int d = 8; d < 32; d <<= 1)
#pragma unroll
        for (int i = 0; i < 2; ++i)
#pragma unroll
            for (int oo = 0; oo < 2; ++oo)
                po[i][oo] += __shfl_xor(po[i][oo], d, 64);

    if (act && fg == 0) {
#pragma unroll
        for (int i = 0; i < 2; ++i)
#pragma unroll
            for (int oo = 0; oo < 2; ++oo)
                atomicAdd(&out[(size_t)(b0 + bg * 2 + i) * ONUM + o0 + oo], po[i][oo]);
    }
}

extern "C" void kernel_launch(void* const* d_in, const int* in_sizes, int n_in,
                              void* d_out, int out_size, void* d_ws, size_t ws_size,
                              hipStream_t stream) {
    const float* x     = (const float*)d_in[0];
    const float* w     = (const float*)d_in[1];
    const float* bias  = (const float*)d_in[2];
    const float* dec_w = (const float*)d_in[3];
    const float* dec_b = (const float*)d_in[4];
    float* out = (float*)d_out;

    init_out<<<(BATCH * ONUM + 255) / 256, 256, 0, stream>>>(dec_b, out);
    lcn_rows<<<(BATCH / 16) * PNUM / 5, 256, 0, stream>>>(x, w, bias, dec_w, out);
}

// Round 6
// 270.941 us; speedup vs baseline: 2.4794x; 2.4794x over previous
//
#include <hip/hip_runtime.h>
#include <stdint.h>

// Problem constants
#define BATCH 512
#define HWIMG 78400      // 280*280
#define WROW  280
#define PNUM  100        // 10x10 patches
#define FNUM  16
#define ONUM  10

typedef __attribute__((address_space(1))) const void cg_void;
typedef __attribute__((address_space(3))) void lds_void;

__global__ __launch_bounds__(256) void init_out(const float* __restrict__ dec_b,
                                                float* __restrict__ out) {
    int i = blockIdx.x * 256 + threadIdx.x;
    if (i < BATCH * ONUM) out[i] = dec_b[i % ONUM];
}

// Block = (pr, pent, 16 batches): pr = patch-row band (28 contiguous image rows),
// pent = which 5 of the 10 patch-columns. Chunk = ONE image row: x staged as
// 16 x 560-B CONTIGUOUS runs (dense DRAM streams), w staged as 80 x 112-B segs.
// 256 threads = kg8 x fg4 x bg8; per lane: i=2 batches, j=4 filters, 5 pc.
//
// LAUNCH BOUNDS: plain (256), NO min-waves arg. Empirically this backend caps
// VGPRs at ~256/min_waves_arg (NOT 512/N): (256,4)->64, (64,3)->84 — both
// spilled acc to scratch (round-2/round-5 FETCH~500MB/WRITE~1GB signature,
// 510us). Default allocation landed at 128 in round 0 with no spill; ~100
// needed here <= 128 cap still allows the LDS-limited 4 blocks/CU.
//
// DMA discipline: ALL global_load_lds ops are FULL-EXEC 64-lane — the LDS-write
// side is wave-uniform base + lane*16 and is NOT safely exec-maskable. The
// 140-f4 per-wave range is covered by 3 ops of 64; op k=2's lanes 12..63 spill
// into wave w+1's leading slots WITH IDENTICAL SOURCE DATA (benign duplicate
// write), and wave 3's tail (gi 560..611) lands in a 56-f4 PAD (buffers are
// [616] not [560]) so it can never corrupt the other dbuf half.
// 6 uniform DMA ops/wave/chunk -> vmcnt(6) keeps next chunk's 6 in flight.
// Sources are uint32 ELEMENT offsets (6 VGPRs) against SGPR bases, not 64-bit
// pointer arrays (24 VGPRs) — register-pressure margin.
// LDS 39.4KB -> 4 blocks/CU (16 waves).
__global__ __launch_bounds__(256) void lcn_rows(
    const float* __restrict__ x,      // (512,1,280,280)
    const float* __restrict__ weight, // (1600,1,28,28)  index (f*100+p)*784
    const float* __restrict__ bias,   // (1600,1)        index  f*100+p
    const float* __restrict__ dec_w,  // (10,1600)       index  o*1600+f*100+p
    float* __restrict__ out)          // (512,10) pre-initialized with dec_b
{
    __shared__ float4 lx[2][616];   // [buf][b*35 + off] b=0..15, off=0..34; 560..615 pad
    __shared__ float4 lw[2][616];   // [buf][(f*5+pc)*7 + k] f=0..15, pc=0..4; pad

    const int t  = threadIdx.x;
    const int kg = t & 7;             // k-column (f4) within the 5-pc window
    const int fg = (t >> 3) & 3;      // filter quad
    const int bg = t >> 5;            // batch pair 0..7
    const int wid = t >> 6;           // wave 0..3
    const int ln  = t & 63;

    const int bx   = blockIdx.x;      // 0..639
    const int pent = bx & 1;          // pent pairs adjacent -> combined full-row streams
    const int bgrp = (bx >> 1) & 31;
    const int pr   = bx >> 6;         // 0..9 (64 consecutive blocks share pr's weights)
    const int b0   = bgrp * 16;
    const int kge  = (kg < 7) ? kg : 0;   // kg==7 duplicates kg==0, masked later

    // ---- DMA source offsets (elements, uint32): wave w stages f4-range
    // [w*140, w*140+140) of lx and lw as 3 full-exec ops. Per-lane divs done
    // ONCE here; per-chunk advance is uniform (+280 x, +28 w elements).
    uint32_t xo[3], wo[3];
#pragma unroll
    for (int k = 0; k < 3; ++k) {
        int gi = wid * 140 + k * 64 + ln;
        if (gi > 559) gi = 559;                    // wave-3 tail -> pad slots, clamped src
        const int b   = gi / 35;                   // local batch 0..15
        const int off = gi % 35;                   // f4 within 560-B run
        xo[k] = (uint32_t)(b0 + b) * HWIMG + (uint32_t)(pr * 28) * WROW
              + (uint32_t)(pent * 140 + off * 4);
        const int seg = gi / 7;                    // (f*5+pc) 0..79
        const int o7  = gi % 7;
        const int f   = seg / 5;
        const int pcl = seg % 5;
        const int p   = pr * 10 + pent * 5 + pcl;
        wo[k] = (uint32_t)(f * PNUM + p) * 784 + (uint32_t)(o7 * 4);
    }

    auto issue = [&](int bb) {
#pragma unroll
        for (int k = 0; k < 3; ++k)
            __builtin_amdgcn_global_load_lds((cg_void*)(x + xo[k]),
                (lds_void*)&lx[bb][wid * 140 + k * 64 + ln], 16, 0, 0);
#pragma unroll
        for (int k = 0; k < 3; ++k)
            __builtin_amdgcn_global_load_lds((cg_void*)(weight + wo[k]),
                (lds_void*)&lw[bb][wid * 140 + k * 64 + ln], 16, 0, 0);
        // advance to next image row
#pragma unroll
        for (int k = 0; k < 3; ++k) { xo[k] += WROW; wo[k] += 28; }
    };

    float acc[5][2][4];
#pragma unroll
    for (int pc = 0; pc < 5; ++pc)
#pragma unroll
        for (int i = 0; i < 2; ++i)
#pragma unroll
            for (int j = 0; j < 4; ++j) acc[pc][i][j] = 0.f;

    issue(0);
    issue(1);

#pragma unroll 1
    for (int c = 0; c < 28; ++c) {
        const int buf = c & 1;
        // chunk c's 6 DMA done; chunk c+1's 6 stay in flight
        if (c < 27) asm volatile("s_waitcnt vmcnt(6)" ::: "memory");
        else        asm volatile("s_waitcnt vmcnt(0)" ::: "memory");
        __builtin_amdgcn_s_barrier();
        asm volatile("" ::: "memory");

#pragma unroll
        for (int pc = 0; pc < 5; ++pc) {
            float4 wvv[4];
#pragma unroll
            for (int j = 0; j < 4; ++j)
                wvv[j] = lw[buf][((fg * 4 + j) * 5 + pc) * 7 + kge];
#pragma unroll
            for (int i = 0; i < 2; ++i) {
                const float4 av = lx[buf][(bg * 2 + i) * 35 + pc * 7 + kge];
#pragma unroll
                for (int j = 0; j < 4; ++j) {
                    acc[pc][i][j] = fmaf(av.x, wvv[j].x, acc[pc][i][j]);
                    acc[pc][i][j] = fmaf(av.y, wvv[j].y, acc[pc][i][j]);
                    acc[pc][i][j] = fmaf(av.z, wvv[j].z, acc[pc][i][j]);
                    acc[pc][i][j] = fmaf(av.w, wvv[j].w, acc[pc][i][j]);
                }
            }
        }

        asm volatile("" ::: "memory");
        __builtin_amdgcn_s_barrier();        // all waves done reading buf
        if (c + 2 < 28) issue(buf);
    }

    // kg==7 computed duplicated (kg==0) data: zero it.
    const float km = (kg < 7) ? 1.f : 0.f;
#pragma unroll
    for (int pc = 0; pc < 5; ++pc)
#pragma unroll
        for (int i = 0; i < 2; ++i)
#pragma unroll
            for (int j = 0; j < 4; ++j) acc[pc][i][j] *= km;

    // Reduce over kg (lane bits 0..2) — butterfly; all lanes end with full sums.
#pragma unroll
    for (int d = 1; d < 8; d <<= 1)
#pragma unroll
        for (int pc = 0; pc < 5; ++pc)
#pragma unroll
            for (int i = 0; i < 2; ++i)
#pragma unroll
                for (int j = 0; j < 4; ++j)
                    acc[pc][i][j] += __shfl_xor(acc[pc][i][j], d, 64);

    // bias + relu (in place)
#pragma unroll
    for (int pc = 0; pc < 5; ++pc) {
        const int p = pr * 10 + pent * 5 + pc;
#pragma unroll
        for (int j = 0; j < 4; ++j) {
            const float bs = bias[(fg * 4 + j) * PNUM + p];
#pragma unroll
            for (int i = 0; i < 2; ++i) {
                float v = acc[pc][i][j] + bs;
                acc[pc][i][j] = v > 0.f ? v : 0.f;
            }
        }
    }

    // Decoder: 10 outputs split across kg lanes 0..4 (2 each).
    float po[2][2];
    const int  o0  = kg * 2;
    const bool act = (kg < 5);
    if (act) {
#pragma unroll
        for (int i = 0; i < 2; ++i) { po[i][0] = 0.f; po[i][1] = 0.f; }
#pragma unroll
        for (int pc = 0; pc < 5; ++pc) {
            const int p = pr * 10 + pent * 5 + pc;
#pragma unroll
            for (int j = 0; j < 4; ++j) {
                const int fidx = (fg * 4 + j) * PNUM + p;
#pragma unroll
                for (int oo = 0; oo < 2; ++oo) {
                    const float dw = dec_w[(size_t)(o0 + oo) * (PNUM * FNUM) + fidx];
#pragma unroll
                    for (int i = 0; i < 2; ++i)
                        po[i][oo] = fmaf(acc[pc][i][j], dw, po[i][oo]);
                }
            }
        }
    } else {
#pragma unroll
        for (int i = 0; i < 2; ++i) { po[i][0] = 0.f; po[i][1] = 0.f; }
    }

    // Reduce over fg (lane bits 3..4); kg/bg bits preserved.
#pragma unroll
    for (int d = 8; d < 32; d <<= 1)
#pragma unroll
        for (int i = 0; i < 2; ++i)
#pragma unroll
            for (int oo = 0; oo < 2; ++oo)
                po[i][oo] += __shfl_xor(po[i][oo], d, 64);

    if (act && fg == 0) {
#pragma unroll
        for (int i = 0; i < 2; ++i)
#pragma unroll
            for (int oo = 0; oo < 2; ++oo)
                atomicAdd(&out[(size_t)(b0 + bg * 2 + i) * ONUM + o0 + oo], po[i][oo]);
    }
}

extern "C" void kernel_launch(void* const* d_in, const int* in_sizes, int n_in,
                              void* d_out, int out_size, void* d_ws, size_t ws_size,
                              hipStream_t stream) {
    const float* x     = (const float*)d_in[0];
    const float* w     = (const float*)d_in[1];
    const float* bias  = (const float*)d_in[2];
    const float* dec_w = (const float*)d_in[3];
    const float* dec_b = (const float*)d_in[4];
    float* out = (float*)d_out;

    init_out<<<(BATCH * ONUM + 255) / 256, 256, 0, stream>>>(dec_b, out);
    lcn_rows<<<(BATCH / 16) * PNUM / 5, 256, 0, stream>>>(x, w, bias, dec_w, out);
}

// Round 7
// 270.589 us; speedup vs baseline: 2.4826x; 1.0013x over previous
//
#include <hip/hip_runtime.h>
#include <stdint.h>

// Problem constants
#define BATCH 512
#define HWIMG 78400      // 280*280
#define WROW  280
#define PNUM  100        // 10x10 patches
#define FNUM  16
#define ONUM  10

typedef __attribute__((address_space(1))) const void cg_void;
typedef __attribute__((address_space(3))) void lds_void;

__global__ __launch_bounds__(256) void init_out(const float* __restrict__ dec_b,
                                                float* __restrict__ out) {
    int i = blockIdx.x * 256 + threadIdx.x;
    if (i < BATCH * ONUM) out[i] = dec_b[i % ONUM];
}

// Block = (pr, pent, 16 batches): pr = patch-row band (28 contiguous image rows),
// pent = which 5 of the 10 patch-columns. Chunk = ONE image row: x staged as
// 16 x 560-B CONTIGUOUS runs, w staged as 80 x 112-B segs.
// 256 threads = kg8 x fg4 x bg8; per lane: i=2 batches, j=4 filters, 5 pc.
//
// XCD PINNING (round-7 change, the single variable): hardware assigns
// dispatch-index d to XCD d%8. Remap f = (bx%8)*80 + bx/8 (bijective, 640%8==0)
// and decode (pr,pent,bgrp) from f, so XCD k hosts flat range [80k,80k+80) =
// slices [2.5k, 2.5k+2.5). All ~32 blocks sharing one (pr,pent) w-slice
// (2.5 MB <= 4 MB per-XCD L2) run on <=2 XCDs -> w is fetched from L3 ~once
// per slice instead of once per XCD per slice (~160-300 MB -> ~60 MB of
// L3-path traffic). Model: kernel is bound by scattered L2-miss service
// (~3 TB/s mixed rate), not any SQ-visible pipe.
//
// LAUNCH BOUNDS: plain (256), NO min-waves arg — backend caps VGPRs at
// ~256/min_waves_arg; (256,4)->64 and (64,3)->84 both spilled acc to scratch
// (FETCH~500MB/WRITE~1GB, 510us). Default lands at ~92-128, no spill.
//
// DMA discipline: ALL global_load_lds ops are FULL-EXEC 64-lane — the LDS-write
// side is wave-uniform base + lane*16 and is NOT safely exec-maskable. The
// 140-f4 per-wave range is covered by 3 ops of 64; op k=2's lanes 12..63 spill
// into wave w+1's leading slots WITH IDENTICAL SOURCE DATA (benign duplicate
// write), and wave 3's tail (gi 560..611) lands in a 56-f4 PAD (buffers are
// [616] not [560]) so it can never corrupt the other dbuf half.
// 6 uniform DMA ops/wave/chunk -> vmcnt(6) keeps next chunk's 6 in flight.
// LDS 39.4KB -> 4 blocks/CU (16 waves).
__global__ __launch_bounds__(256) void lcn_rows(
    const float* __restrict__ x,      // (512,1,280,280)
    const float* __restrict__ weight, // (1600,1,28,28)  index (f*100+p)*784
    const float* __restrict__ bias,   // (1600,1)        index  f*100+p
    const float* __restrict__ dec_w,  // (10,1600)       index  o*1600+f*100+p
    float* __restrict__ out)          // (512,10) pre-initialized with dec_b
{
    __shared__ float4 lx[2][616];   // [buf][b*35 + off] b=0..15, off=0..34; 560..615 pad
    __shared__ float4 lw[2][616];   // [buf][(f*5+pc)*7 + k] f=0..15, pc=0..4; pad

    const int t  = threadIdx.x;
    const int kg = t & 7;             // k-column (f4) within the 5-pc window
    const int fg = (t >> 3) & 3;      // filter quad
    const int bg = t >> 5;            // batch pair 0..7
    const int wid = t >> 6;           // wave 0..3
    const int ln  = t & 63;

    // ---- XCD-pinned decode (see header). f = slice*32 + bgrp,
    // slice = pr*2 + pent.
    const int bx = blockIdx.x;        // 0..639
    const int f_ = (bx & 7) * 80 + (bx >> 3);
    const int pr   = f_ >> 6;         // 0..9
    const int pent = (f_ >> 5) & 1;   // 0..1
    const int bgrp = f_ & 31;         // 0..31
    const int b0   = bgrp * 16;
    const int kge  = (kg < 7) ? kg : 0;   // kg==7 duplicates kg==0, masked later

    // ---- DMA source offsets (elements, uint32): wave w stages f4-range
    // [w*140, w*140+140) of lx and lw as 3 full-exec ops. Per-lane divs done
    // ONCE here; per-chunk advance is uniform (+280 x, +28 w elements).
    uint32_t xo[3], wo[3];
#pragma unroll
    for (int k = 0; k < 3; ++k) {
        int gi = wid * 140 + k * 64 + ln;
        if (gi > 559) gi = 559;                    // wave-3 tail -> pad slots, clamped src
        const int b   = gi / 35;                   // local batch 0..15
        const int off = gi % 35;                   // f4 within 560-B run
        xo[k] = (uint32_t)(b0 + b) * HWIMG + (uint32_t)(pr * 28) * WROW
              + (uint32_t)(pent * 140 + off * 4);
        const int seg = gi / 7;                    // (f*5+pc) 0..79
        const int o7  = gi % 7;
        const int ff  = seg / 5;
        const int pcl = seg % 5;
        const int p   = pr * 10 + pent * 5 + pcl;
        wo[k] = (uint32_t)(ff * PNUM + p) * 784 + (uint32_t)(o7 * 4);
    }

    auto issue = [&](int bb) {
#pragma unroll
        for (int k = 0; k < 3; ++k)
            __builtin_amdgcn_global_load_lds((cg_void*)(x + xo[k]),
                (lds_void*)&lx[bb][wid * 140 + k * 64 + ln], 16, 0, 0);
#pragma unroll
        for (int k = 0; k < 3; ++k)
            __builtin_amdgcn_global_load_lds((cg_void*)(weight + wo[k]),
                (lds_void*)&lw[bb][wid * 140 + k * 64 + ln], 16, 0, 0);
        // advance to next image row
#pragma unroll
        for (int k = 0; k < 3; ++k) { xo[k] += WROW; wo[k] += 28; }
    };

    float acc[5][2][4];
#pragma unroll
    for (int pc = 0; pc < 5; ++pc)
#pragma unroll
        for (int i = 0; i < 2; ++i)
#pragma unroll
            for (int j = 0; j < 4; ++j) acc[pc][i][j] = 0.f;

    issue(0);
    issue(1);

#pragma unroll 1
    for (int c = 0; c < 28; ++c) {
        const int buf = c & 1;
        // chunk c's 6 DMA done; chunk c+1's 6 stay in flight
        if (c < 27) asm volatile("s_waitcnt vmcnt(6)" ::: "memory");
        else        asm volatile("s_waitcnt vmcnt(0)" ::: "memory");
        __builtin_amdgcn_s_barrier();
        asm volatile("" ::: "memory");

#pragma unroll
        for (int pc = 0; pc < 5; ++pc) {
            float4 wvv[4];
#pragma unroll
            for (int j = 0; j < 4; ++j)
                wvv[j] = lw[buf][((fg * 4 + j) * 5 + pc) * 7 + kge];
#pragma unroll
            for (int i = 0; i < 2; ++i) {
                const float4 av = lx[buf][(bg * 2 + i) * 35 + pc * 7 + kge];
#pragma unroll
                for (int j = 0; j < 4; ++j) {
                    acc[pc][i][j] = fmaf(av.x, wvv[j].x, acc[pc][i][j]);
                    acc[pc][i][j] = fmaf(av.y, wvv[j].y, acc[pc][i][j]);
                    acc[pc][i][j] = fmaf(av.z, wvv[j].z, acc[pc][i][j]);
                    acc[pc][i][j] = fmaf(av.w, wvv[j].w, acc[pc][i][j]);
                }
            }
        }

        asm volatile("" ::: "memory");
        __builtin_amdgcn_s_barrier();        // all waves done reading buf
        if (c + 2 < 28) issue(buf);
    }

    // kg==7 computed duplicated (kg==0) data: zero it.
    const float km = (kg < 7) ? 1.f : 0.f;
#pragma unroll
    for (int pc = 0; pc < 5; ++pc)
#pragma unroll
        for (int i = 0; i < 2; ++i)
#pragma unroll
            for (int j = 0; j < 4; ++j) acc[pc][i][j] *= km;

    // Reduce over kg (lane bits 0..2) — butterfly; all lanes end with full sums.
#pragma unroll
    for (int d = 1; d < 8; d <<= 1)
#pragma unroll
        for (int pc = 0; pc < 5; ++pc)
#pragma unroll
            for (int i = 0; i < 2; ++i)
#pragma unroll
                for (int j = 0; j < 4; ++j)
                    acc[pc][i][j] += __shfl_xor(acc[pc][i][j], d, 64);

    // bias + relu (in place)
#pragma unroll
    for (int pc = 0; pc < 5; ++pc) {
        const int p = pr * 10 + pent * 5 + pc;
#pragma unroll
        for (int j = 0; j < 4; ++j) {
            const float bs = bias[(fg * 4 + j) * PNUM + p];
#pragma unroll
            for (int i = 0; i < 2; ++i) {
                float v = acc[pc][i][j] + bs;
                acc[pc][i][j] = v > 0.f ? v : 0.f;
            }
        }
    }

    // Decoder: 10 outputs split across kg lanes 0..4 (2 each).
    float po[2][2];
    const int  o0  = kg * 2;
    const bool act = (kg < 5);
    if (act) {
#pragma unroll
        for (int i = 0; i < 2; ++i) { po[i][0] = 0.f; po[i][1] = 0.f; }
#pragma unroll
        for (int pc = 0; pc < 5; ++pc) {
            const int p = pr * 10 + pent * 5 + pc;
#pragma unroll
            for (int j = 0; j < 4; ++j) {
                const int fidx = (fg * 4 + j) * PNUM + p;
#pragma unroll
                for (int oo = 0; oo < 2; ++oo) {
                    const float dw = dec_w[(size_t)(o0 + oo) * (PNUM * FNUM) + fidx];
#pragma unroll
                    for (int i = 0; i < 2; ++i)
                        po[i][oo] = fmaf(acc[pc][i][j], dw, po[i][oo]);
                }
            }
        }
    } else {
#pragma unroll
        for (int i = 0; i < 2; ++i) { po[i][0] = 0.f; po[i][1] = 0.f; }
    }

    // Reduce over fg (lane bits 3..4); kg/bg bits preserved.
#pragma unroll
    for (int d = 8; d < 32; d <<= 1)
#pragma unroll
        for (int i = 0; i < 2; ++i)
#pragma unroll
            for (int oo = 0; oo < 2; ++oo)
                po[i][oo] += __shfl_xor(po[i][oo], d, 64);

    if (act && fg == 0) {
#pragma unroll
        for (int i = 0; i < 2; ++i)
#pragma unroll
            for (int oo = 0; oo < 2; ++oo)
                atomicAdd(&out[(size_t)(b0 + bg * 2 + i) * ONUM + o0 + oo], po[i][oo]);
    }
}

extern "C" void kernel_launch(void* const* d_in, const int* in_sizes, int n_in,
                              void* d_out, int out_size, void* d_ws, size_t ws_size,
                              hipStream_t stream) {
    const float* x     = (const float*)d_in[0];
    const float* w     = (const float*)d_in[1];
    const float* bias  = (const float*)d_in[2];
    const float* dec_w = (const float*)d_in[3];
    const float* dec_b = (const float*)d_in[4];
    float* out = (float*)d_out;

    init_out<<<(BATCH * ONUM + 255) / 256, 256, 0, stream>>>(dec_b, out);
    lcn_rows<<<(BATCH / 16) * PNUM / 5, 256, 0, stream>>>(x, w, bias, dec_w, out);
}